// Round 3
// baseline (766.002 us; speedup 1.0000x reference)
//
#include <hip/hip_runtime.h>
#include <math.h>

typedef __attribute__((ext_vector_type(4))) float f32x4;
typedef __attribute__((ext_vector_type(8))) short s16x8;
typedef __attribute__((ext_vector_type(4))) short s16x4;
typedef unsigned short ushort_t;

#define MFMA16(a, b, c) __builtin_amdgcn_mfma_f32_16x16x32_bf16((a), (b), (c), 0, 0, 0)

// ---------------- workspace byte offsets ----------------
#define WO_CTX    0u          // 32768
#define WO_HDN    32768u      // 2048
#define WO_BNSUM  34816u      // 1024
#define WO_BNSQ   35840u      // 1024
#define WO_SCALE  36864u      // 1024
#define WO_SHIFT  37888u      // 1024
#define WO_COEF   40960u      // 4194304
#define WO_BMT_H  4235264u    // 8192  (64x64 bf16)
#define WO_BMT_L  4243456u
#define WO_FARE_H 4251648u    // 16384 (64x128)
#define WO_FARE_L 4268032u
#define WO_FAIM_H 4284416u
#define WO_FAIM_L 4300800u
#define WO_FDRE_H 4317184u
#define WO_FDRE_L 4333568u
#define WO_FDIM_H 4349952u
#define WO_FDIM_L 4366336u
#define WO_DTT_H  4382720u    // 8192 (64x64)
#define WO_DTT_L  4390912u
#define WO_CW_H   4399104u    // 131072 (256x256)
#define WO_CW_L   4530176u
#define WO_BASP   4661248u    // 114688 (1792*8*2 fp32, [q][k][{Re,Im}])
#define WO_YBF    4775936u    // 51380224 (8192*3136 bf16)

__device__ __forceinline__ ushort_t f2bf(float f) {
  unsigned int u = __builtin_bit_cast(unsigned int, f);
  unsigned int r = (u + 0x7fffu + ((u >> 16) & 1u)) >> 16;
  return (ushort_t)r;
}
__device__ __forceinline__ float bf2f(ushort_t h) {
  unsigned int u = ((unsigned int)h) << 16;
  return __builtin_bit_cast(float, u);
}
__device__ __forceinline__ s16x8 pack8(float4 a, float4 b) {
  s16x8 r;
  r[0] = (short)f2bf(a.x); r[1] = (short)f2bf(a.y);
  r[2] = (short)f2bf(a.z); r[3] = (short)f2bf(a.w);
  r[4] = (short)f2bf(b.x); r[5] = (short)f2bf(b.y);
  r[6] = (short)f2bf(b.z); r[7] = (short)f2bf(b.w);
  return r;
}

// ---------------- constant-matrix math (double precision) ----------------
__device__ double bmat_val(int w, int vv) {
  const int v = vv & 31;
  const bool isI = vv >= 32;
  double accR = 0.0, accI = 0.0;
  for (int wp = 0; wp < 62; ++wp) {
    const double src = (wp + 0.5) * (56.0 / 62.0) - 0.5;
    const int w0 = (int)floor(src);
    const double f = src - (double)w0;
    const double s0 = (w0 >= 0 && w0 <= 55) ? (1.0 - f) : 0.0;
    const double s1 = (w0 + 1 >= 0 && w0 + 1 <= 55) ? f : 0.0;
    const double ssum = s0 + s1;
    double wgt = 0.0;
    if (w == w0) wgt = s0 / ssum;
    else if (w == w0 + 1) wgt = s1 / ssum;
    if (wgt != 0.0) {
      const int p = (v * wp) % 62;
      const double ang = 6.283185307179586476925286766559 * (double)p / 62.0;
      accR += wgt * cos(ang);
      accI -= wgt * sin(ang);
    }
  }
  const double nrm = 1.0 / sqrt(3472.0);
  return (isI ? accI : accR) * nrm;
}

__device__ double dt_val_fixed(int kk, int wq) {
  const int v = (kk < 32) ? kk : kk - 32;
  const bool isI = kk >= 32;
  const double ks = 62.0 / 56.0;
  const double src = (wq + 0.5) * ks - 0.5;
  double wsum = 0.0;
  for (int wp = 0; wp < 62; ++wp) {
    const double xx = fabs(src - (double)wp) / ks;
    if (xx < 1.0) wsum += 1.0 - xx;
  }
  const double cv = (v == 0 || v == 31) ? 1.0 : 2.0;
  double accR = 0.0, accI = 0.0;
  for (int wp = 0; wp < 62; ++wp) {
    const double xx = fabs(src - (double)wp) / ks;
    if (xx >= 1.0) continue;
    const double wgt = (1.0 - xx) / wsum;
    double cc, ss;
    if (v == 0)       { cc = 1.0; ss = 0.0; }
    else if (v == 31) { cc = (wp & 1) ? -1.0 : 1.0; ss = 0.0; }
    else {
      const int p = (v * wp) % 62;
      const double ang = 6.283185307179586476925286766559 * (double)p / 62.0;
      cc = cos(ang); ss = sin(ang);
    }
    accR += wgt * cv * cc;
    accI -= wgt * cv * ss;
  }
  const double nrm = 1.0 / sqrt(3472.0);
  return (isI ? accI : accR) * nrm;
}

__device__ __forceinline__ void emit_hilo(ushort_t* hp, ushort_t* lp, int off, double val) {
  const float fv = (float)val;
  const ushort_t h = f2bf(fv);
  const float hf = bf2f(h);
  const ushort_t l = f2bf((float)(val - (double)hf));
  hp[off] = h;
  lp[off] = l;
}

__global__ void k_const(const float* __restrict__ conv_w,
                        const float* __restrict__ basR, const float* __restrict__ basI,
                        ushort_t* BmT_h, ushort_t* BmT_l,
                        ushort_t* FARe_h, ushort_t* FARe_l,
                        ushort_t* FAIm_h, ushort_t* FAIm_l,
                        ushort_t* FDRe_h, ushort_t* FDRe_l,
                        ushort_t* FDIm_h, ushort_t* FDIm_l,
                        ushort_t* DtT_h, ushort_t* DtT_l,
                        ushort_t* W_h, ushort_t* W_l,
                        float* basP) {
  const int idx = blockIdx.x * 256 + threadIdx.x;
  if (idx < 4096) {
    // BmT[vv][k=w], k>=56 zero
    const int vv = idx >> 6, k = idx & 63;
    const double v = (k < 56) ? bmat_val(k, vv) : 0.0;
    emit_hilo(BmT_h, BmT_l, idx, v);
  } else if (idx < 36864) {
    const int t = (idx - 4096) & 8191;
    const int which = (idx - 4096) >> 13;  // 0 FARe, 1 FAIm, 2 FDRe, 3 FDIm
    const int row = t >> 7, k = t & 127;
    double val = 0.0;
    if (row < 56 && k < 112) {
      const int h = (k < 56) ? k : k - 56;
      const double ang = 6.283185307179586476925286766559 *
                         (double)((row * h) % 56) / 56.0;
      const double c = cos(ang), s = sin(ang);
      const bool lowk = (k < 56);
      // fwd: e^{-i t} -> Re=[c|s], Im=[-s|c]; inv: e^{+i t} -> Re=[c|-s], Im=[s|c]
      if (which == 0)      val = lowk ? c : s;
      else if (which == 1) val = lowk ? -s : c;
      else if (which == 2) val = lowk ? c : -s;
      else                 val = lowk ? s : c;
    }
    ushort_t* hp = (which == 0) ? FARe_h : (which == 1) ? FAIm_h : (which == 2) ? FDRe_h : FDIm_h;
    ushort_t* lp = (which == 0) ? FARe_l : (which == 1) ? FAIm_l : (which == 2) ? FDRe_l : FDIm_l;
    emit_hilo(hp, lp, t, val);
  } else if (idx < 40960) {
    const int t = idx - 36864;
    const int w = t >> 6, kk = t & 63;
    const double v = (w < 56) ? dt_val_fixed(kk, w) : 0.0;
    emit_hilo(DtT_h, DtT_l, t, v);
  } else if (idx < 106496) {
    const int t = idx - 40960;
    emit_hilo(W_h, W_l, t, (double)conv_w[t]);
  } else if (idx < 135168) {
    const int t = idx - 106496;      // [q][k][{Re,Im}]
    const int q = t >> 4, r = t & 15, k = r >> 1;
    basP[t] = (r & 1) ? basI[k * 1792 + q] : basR[k * 1792 + q];
  }
}

// ---------------- GAP ----------------
__global__ __launch_bounds__(256) void k_gap(const float* __restrict__ x,
                                             float* __restrict__ ctx) {
  const int img = blockIdx.x;
  const int tid = threadIdx.x;
  const float4* p4 = (const float4*)(x + (size_t)img * 3136);
  float s = 0.f;
  for (int i = tid; i < 784; i += 256) {
    const float4 v = p4[i];
    s += v.x + v.y + v.z + v.w;
  }
  for (int off = 32; off > 0; off >>= 1) s += __shfl_down(s, off, 64);
  __shared__ float ls[4];
  if ((tid & 63) == 0) ls[tid >> 6] = s;
  __syncthreads();
  if (tid == 0) ctx[img] = (ls[0] + ls[1] + ls[2] + ls[3]) * (1.0f / 3136.0f);
}

// ---------------- fc1 + LN + ReLU ----------------
__global__ void k_mlp(const float* __restrict__ ctx, const float* __restrict__ fc1_w,
                      const float* __restrict__ fc1_b, const float* __restrict__ ln_g,
                      const float* __restrict__ ln_b, float* __restrict__ hdn) {
  const int b = blockIdx.x;
  const int j = threadIdx.x;
  __shared__ float h[16];
  if (j < 16) {
    const float* cr = ctx + b * 256;
    const float* wr = fc1_w + j * 256;
    float acc = fc1_b[j];
    for (int c0 = 0; c0 < 256; ++c0) acc = fmaf(cr[c0], wr[c0], acc);
    h[j] = acc;
  }
  __syncthreads();
  if (j < 16) {
    float mu = 0.f, m2 = 0.f;
    for (int t = 0; t < 16; ++t) { mu += h[t]; m2 += h[t] * h[t]; }
    mu *= 0.0625f; m2 *= 0.0625f;
    const float var = m2 - mu * mu;
    const float val = (h[j] - mu) / sqrtf(var + 1e-5f) * ln_g[j] + ln_b[j];
    hdn[b * 16 + j] = fmaxf(val, 0.f);
  }
}

// ---------------- fourier head + softmax ----------------
__global__ __launch_bounds__(256) void k_coeffs(const float* __restrict__ hdn,
                                                const float* __restrict__ fh_w,
                                                const float* __restrict__ fh_b,
                                                float* __restrict__ coeffs) {
  const int gid = blockIdx.x * 256 + threadIdx.x;
  const int b = gid >> 12;
  const int cm = gid & 4095;
  float hv[16];
  const float* hp = hdn + b * 16;
#pragma unroll
  for (int j = 0; j < 16; ++j) hv[j] = hp[j];
  const int row0 = cm * 8;
  float a[8];
  float mx = -1e30f;
#pragma unroll
  for (int k = 0; k < 8; ++k) {
    const float* wr = fh_w + (size_t)(row0 + k) * 16;
    float acc = fh_b[row0 + k];
#pragma unroll
    for (int j = 0; j < 16; ++j) acc = fmaf(hv[j], wr[j], acc);
    a[k] = acc;
    mx = fmaxf(mx, acc);
  }
  float s = 0.f;
#pragma unroll
  for (int k = 0; k < 8; ++k) { a[k] = expf(a[k] - mx); s += a[k]; }
  const float inv = 1.f / s;
  float* outp = coeffs + (size_t)gid * 8;
#pragma unroll
  for (int k = 0; k < 8; ++k) outp[k] = a[k] * inv;
}

// ---------------- fused spectral branch: 4 images/block, one wave per image ----------------
// Per-wave private pipeline (no inter-stage barriers). Single 9200 B LDS buffer
// per wave reused x1T -> x2T -> ta (B-fragments hoisted to VGPRs before overwrite).
// One cooperative G-phase (basis loaded once per block, coeffs via uniform s_load).
__global__ __launch_bounds__(256) void k_fft(
    const float* __restrict__ x, const float* __restrict__ coeffs,
    const float* __restrict__ basP,
    const ushort_t* __restrict__ BmT_h, const ushort_t* __restrict__ BmT_l,
    const ushort_t* __restrict__ FARe_h, const ushort_t* __restrict__ FARe_l,
    const ushort_t* __restrict__ FAIm_h, const ushort_t* __restrict__ FAIm_l,
    const ushort_t* __restrict__ FDRe_h, const ushort_t* __restrict__ FDRe_l,
    const ushort_t* __restrict__ FDIm_h, const ushort_t* __restrict__ FDIm_l,
    const ushort_t* __restrict__ DtT_h, const ushort_t* __restrict__ DtT_l,
    ushort_t* __restrict__ ybf) {
  __shared__ __align__(16) ushort_t buf[4 * 4600];   // 36800 B (9200/wave)
  __shared__ unsigned int Gsh[4 * 1792];             // 28672 B, packed bf16 Re|Im
  const int img0 = blockIdx.x * 4;
  const int tid = threadIdx.x;
  const int wave = tid >> 6, lane = tid & 63, col = lane & 15, quad = lane >> 4;
  const f32x4 zf = {0.f, 0.f, 0.f, 0.f};
  ushort_t* bufw = buf + wave * 4600;
  const int img = img0 + wave;

  // zero the k=112..127 stripe of rows 0..31 (read-but-unwritten; NaN guard)
  {
    const int row = lane >> 1, half = lane & 1;
    s16x8 z8;
#pragma unroll
    for (int j = 0; j < 8; ++j) z8[j] = 0;
    *(s16x8*)&bufw[row * 136 + 112 + half * 8] = z8;
  }

  // ---- G phase: cooperative, m-grouped; basis loaded once per block ----
  for (int it = 0; it < 8; ++it) {
    if (tid < 224) {
      const int m = it * 2 + (tid >= 112 ? 1 : 0);
      const int idx = (tid >= 112) ? tid - 112 : tid;
      const int u = (m >> 2) * 14 + (idx >> 3);
      const int v = (m & 3) * 8 + (idx & 7);
      const int q = u * 32 + v;
      const float4* bp = (const float4*)(basP + q * 16);
      const float4 b0 = bp[0], b1 = bp[1], b2 = bp[2], b3 = bp[3];
#pragma unroll
      for (int i = 0; i < 4; ++i) {
        const float* cm = coeffs + ((size_t)(img0 + i) * 16 + m) * 8;  // uniform -> s_load
        float gr = 0.f, gi = 0.f;
        gr = fmaf(cm[0], b0.x, gr); gi = fmaf(cm[0], b0.y, gi);
        gr = fmaf(cm[1], b0.z, gr); gi = fmaf(cm[1], b0.w, gi);
        gr = fmaf(cm[2], b1.x, gr); gi = fmaf(cm[2], b1.y, gi);
        gr = fmaf(cm[3], b1.z, gr); gi = fmaf(cm[3], b1.w, gi);
        gr = fmaf(cm[4], b2.x, gr); gi = fmaf(cm[4], b2.y, gi);
        gr = fmaf(cm[5], b2.z, gr); gi = fmaf(cm[5], b2.w, gi);
        gr = fmaf(cm[6], b3.x, gr); gi = fmaf(cm[6], b3.y, gi);
        gr = fmaf(cm[7], b3.z, gr); gi = fmaf(cm[7], b3.w, gi);
        Gsh[i * 1792 + q] = (((unsigned int)f2bf(gr)) << 16) | (unsigned int)f2bf(gi);
      }
    }
  }
  __syncthreads();

  // ---- stage b: x1 = x @ Bmat ; write x1T[v][k=h|56+h] ----
  {
    const float* xim = x + (size_t)img * 3136;
#pragma unroll
    for (int mt = 0; mt < 4; ++mt) {
      const int h = mt * 16 + col;
      const int hc = (h < 56) ? h : 55;              // clamp (page-edge guard)
      const float* xr = xim + hc * 56;
      const float4 xa0 = *(const float4*)(xr + quad * 8);
      const float4 xa1 = *(const float4*)(xr + quad * 8 + 4);
      const s16x8 a0 = pack8(xa0, xa1);
      s16x8 a1;
      if (quad < 3) {
        const float4 xb0 = *(const float4*)(xr + 32 + quad * 8);
        const float4 xb1 = *(const float4*)(xr + 36 + quad * 8);
        a1 = pack8(xb0, xb1);
      } else {
#pragma unroll
        for (int j = 0; j < 8; ++j) a1[j] = 0;       // w>=56 (zero, B rows zero too)
      }
      const int h0 = mt * 16 + quad * 4;
#pragma unroll
      for (int nt = 0; nt < 4; ++nt) {
        const int nrow = nt * 16 + col;              // vv
        const s16x8 bh0 = *(const s16x8*)&BmT_h[nrow * 64 + quad * 8];
        const s16x8 bl0 = *(const s16x8*)&BmT_l[nrow * 64 + quad * 8];
        const s16x8 bh1 = *(const s16x8*)&BmT_h[nrow * 64 + 32 + quad * 8];
        const s16x8 bl1 = *(const s16x8*)&BmT_l[nrow * 64 + 32 + quad * 8];
        f32x4 acc = zf;
        acc = MFMA16(a0, bh0, acc);
        acc = MFMA16(a0, bl0, acc);
        acc = MFMA16(a1, bh1, acc);
        acc = MFMA16(a1, bl1, acc);
        if (h0 < 56) {
          s16x4 p;
          p[0] = (short)f2bf(acc[0]); p[1] = (short)f2bf(acc[1]);
          p[2] = (short)f2bf(acc[2]); p[3] = (short)f2bf(acc[3]);
          const int vr = nrow & 31;
          const int kk = (nrow < 32) ? h0 : 56 + h0;
          *(s16x4*)&bufw[vr * 136 + kk] = p;
        }
      }
    }
  }

  // ---- stage c: X2 = FA @ x1 (stacked-K complex), filter by G -> x2T ----
  {
    s16x8 bf[2][4];
#pragma unroll
    for (int nt = 0; nt < 2; ++nt)
#pragma unroll
      for (int ks = 0; ks < 4; ++ks)
        bf[nt][ks] = *(const s16x8*)&bufw[(nt * 16 + col) * 136 + ks * 32 + quad * 8];

#pragma unroll
    for (int mt = 0; mt < 4; ++mt) {
      f32x4 aR[2] = {zf, zf}, aI[2] = {zf, zf};
#pragma unroll
      for (int ks = 0; ks < 4; ++ks) {
        const int off = (mt * 16 + col) * 128 + ks * 32 + quad * 8;
        const s16x8 rh = *(const s16x8*)&FARe_h[off];
        const s16x8 rl = *(const s16x8*)&FARe_l[off];
        const s16x8 ih = *(const s16x8*)&FAIm_h[off];
        const s16x8 il = *(const s16x8*)&FAIm_l[off];
#pragma unroll
        for (int nt = 0; nt < 2; ++nt) {
          aR[nt] = MFMA16(rh, bf[nt][ks], aR[nt]);
          aR[nt] = MFMA16(rl, bf[nt][ks], aR[nt]);
          aI[nt] = MFMA16(ih, bf[nt][ks], aI[nt]);
          aI[nt] = MFMA16(il, bf[nt][ks], aI[nt]);
        }
      }
      const int u0 = mt * 16 + quad * 4;
      if (u0 < 56) {
#pragma unroll
        for (int nt = 0; nt < 2; ++nt) {
          const int v = nt * 16 + col;
          s16x4 pR, pI;
#pragma unroll
          for (int r = 0; r < 4; ++r) {
            const unsigned int gp = Gsh[wave * 1792 + (u0 + r) * 32 + v];
            const float gr = __builtin_bit_cast(float, gp & 0xffff0000u);
            const float gi = __builtin_bit_cast(float, gp << 16);
            const float re = aR[nt][r] * gr - aI[nt][r] * gi;
            const float im = aR[nt][r] * gi + aI[nt][r] * gr;
            pR[r] = (short)f2bf(re);
            pI[r] = (short)f2bf(im);
          }
          *(s16x4*)&bufw[v * 136 + u0] = pR;
          *(s16x4*)&bufw[v * 136 + 56 + u0] = pI;
        }
      }
    }
  }

  // ---- stage d: T = FD @ X2f -> ta (A-layout, stride 72, rows h<56) ----
  {
    s16x8 bf[2][4];
#pragma unroll
    for (int nt = 0; nt < 2; ++nt)
#pragma unroll
      for (int ks = 0; ks < 4; ++ks)
        bf[nt][ks] = *(const s16x8*)&bufw[(nt * 16 + col) * 136 + ks * 32 + quad * 8];

#pragma unroll
    for (int mt = 0; mt < 4; ++mt) {
      f32x4 aR[2] = {zf, zf}, aI[2] = {zf, zf};
#pragma unroll
      for (int ks = 0; ks < 4; ++ks) {
        const int off = (mt * 16 + col) * 128 + ks * 32 + quad * 8;
        const s16x8 rh = *(const s16x8*)&FDRe_h[off];
        const s16x8 rl = *(const s16x8*)&FDRe_l[off];
        const s16x8 ih = *(const s16x8*)&FDIm_h[off];
        const s16x8 il = *(const s16x8*)&FDIm_l[off];
#pragma unroll
        for (int nt = 0; nt < 2; ++nt) {
          aR[nt] = MFMA16(rh, bf[nt][ks], aR[nt]);
          aR[nt] = MFMA16(rl, bf[nt][ks], aR[nt]);
          aI[nt] = MFMA16(ih, bf[nt][ks], aI[nt]);
          aI[nt] = MFMA16(il, bf[nt][ks], aI[nt]);
        }
      }
      const int h0 = mt * 16 + quad * 4;
      if (h0 < 56) {
#pragma unroll
        for (int nt = 0; nt < 2; ++nt) {
          const int v = nt * 16 + col;
#pragma unroll
          for (int r = 0; r < 4; ++r) {
            bufw[(h0 + r) * 72 + v]      = f2bf(aR[nt][r]);
            bufw[(h0 + r) * 72 + 32 + v] = f2bf(aI[nt][r]);
          }
        }
      }
    }
  }

  // ---- stage e: y = T @ DtStack (K=64), store bf16 pixel-major ----
  {
    ushort_t* yo = ybf + (size_t)img * 3136;
#pragma unroll
    for (int mt = 0; mt < 4; ++mt) {
      const int arow = (mt * 16 + col) * 72;
      const s16x8 a0 = *(const s16x8*)&bufw[arow + quad * 8];
      const s16x8 a1 = *(const s16x8*)&bufw[arow + 32 + quad * 8];
      const int h0 = mt * 16 + quad * 4;
#pragma unroll
      for (int nt = 0; nt < 4; ++nt) {
        const int w = nt * 16 + col;
        const s16x8 bh0 = *(const s16x8*)&DtT_h[w * 64 + quad * 8];
        const s16x8 bl0 = *(const s16x8*)&DtT_l[w * 64 + quad * 8];
        const s16x8 bh1 = *(const s16x8*)&DtT_h[w * 64 + 32 + quad * 8];
        const s16x8 bl1 = *(const s16x8*)&DtT_l[w * 64 + 32 + quad * 8];
        f32x4 acc = zf;
        acc = MFMA16(a0, bh0, acc);
        acc = MFMA16(a0, bl0, acc);
        acc = MFMA16(a1, bh1, acc);
        acc = MFMA16(a1, bl1, acc);
        if (h0 < 56 && w < 56) {
#pragma unroll
          for (int r = 0; r < 4; ++r) yo[(h0 + r) * 56 + w] = f2bf(acc[r]);
        }
      }
    }
  }
}

// ---------------- 1x1 conv via MFMA, LDS-staged transpose, fused BN sums ----------------
__global__ __launch_bounds__(256) void k_conv(const ushort_t* __restrict__ ybf,
                                              const ushort_t* __restrict__ W_h,
                                              const ushort_t* __restrict__ W_l,
                                              float* __restrict__ z,
                                              float* __restrict__ bnsum,
                                              float* __restrict__ bnsq) {
  __shared__ __align__(16) ushort_t Ys[256 * 40];  // [pix_local][ch_local], 20480 B
  const int pb = blockIdx.x;   // 13 blocks of 256 pixels (last ragged)
  const int oh = blockIdx.y;   // 2 x 128 out-channels
  const int b  = blockIdx.z;
  const int tid = threadIdx.x;
  const int wave = tid >> 6, lane = tid & 63, col = lane & 15, quad = lane >> 4;
  const f32x4 zf = {0.f, 0.f, 0.f, 0.f};
  f32x4 acc[8][4];
#pragma unroll
  for (int mt = 0; mt < 8; ++mt)
#pragma unroll
    for (int i = 0; i < 4; ++i) acc[mt][i] = zf;

  const size_t ybase = (size_t)b * 256 * 3136;
  const int pbase = pb * 256;
  const int chl = tid >> 3;   // 0..31
  const int pg  = tid & 7;    // 0..7

  for (int ks = 0; ks < 8; ++ks) {
    const int c = ks * 32 + chl;
    s16x8 ld[4];
#pragma unroll
    for (int j = 0; j < 4; ++j) {
      const int p = pbase + pg * 32 + j * 8;
      if (p < 3136) {
        ld[j] = *(const s16x8*)&ybf[ybase + (size_t)c * 3136 + p];
      } else {
#pragma unroll
        for (int e = 0; e < 8; ++e) ld[j][e] = 0;
      }
    }
    __syncthreads();  // previous iteration's fragment reads complete
#pragma unroll
    for (int j = 0; j < 4; ++j) {
      const int pl = pg * 32 + j * 8;
#pragma unroll
      for (int e = 0; e < 8; ++e) Ys[(pl + e) * 40 + chl] = (ushort_t)ld[j][e];
    }
    __syncthreads();

    s16x8 bfrag[4];
#pragma unroll
    for (int i = 0; i < 4; ++i) {
      const int pl = wave * 64 + i * 16 + col;
      bfrag[i] = *(const s16x8*)&Ys[pl * 40 + quad * 8];
    }
#pragma unroll
    for (int mt = 0; mt < 8; ++mt) {
      const int orow = oh * 128 + mt * 16 + col;
      const s16x8 ah = *(const s16x8*)&W_h[orow * 256 + ks * 32 + quad * 8];
      const s16x8 al = *(const s16x8*)&W_l[orow * 256 + ks * 32 + quad * 8];
#pragma unroll
      for (int i = 0; i < 4; ++i) {
        acc[mt][i] = MFMA16(ah, bfrag[i], acc[mt][i]);
        acc[mt][i] = MFMA16(al, bfrag[i], acc[mt][i]);
      }
    }
  }

  // epilogue: store + fused BN partial sums
#pragma unroll
  for (int mt = 0; mt < 8; ++mt) {
    float s[4] = {0.f, 0.f, 0.f, 0.f}, s2[4] = {0.f, 0.f, 0.f, 0.f};
#pragma unroll
    for (int i = 0; i < 4; ++i) {
      const int p = pbase + wave * 64 + i * 16 + col;
      if (p < 3136) {
#pragma unroll
        for (int r = 0; r < 4; ++r) {
          const int o = oh * 128 + mt * 16 + quad * 4 + r;
          const float v = acc[mt][i][r];
          z[((size_t)b * 256 + o) * 3136 + p] = v;
          s[r] += v;
          s2[r] += v * v;
        }
      }
    }
#pragma unroll
    for (int mask = 1; mask < 16; mask <<= 1) {
#pragma unroll
      for (int r = 0; r < 4; ++r) {
        s[r] += __shfl_xor(s[r], mask, 64);
        s2[r] += __shfl_xor(s2[r], mask, 64);
      }
    }
    if (col == 0) {
#pragma unroll
      for (int r = 0; r < 4; ++r) {
        const int o = oh * 128 + mt * 16 + quad * 4 + r;
        atomicAdd(bnsum + o, s[r]);
        atomicAdd(bnsq + o, s2[r]);
      }
    }
  }
}

__global__ void k_bnstats(const float* __restrict__ bnsum, const float* __restrict__ bnsq,
                          const float* __restrict__ bn_g, const float* __restrict__ bn_b,
                          float* __restrict__ scale, float* __restrict__ shift) {
  const int o = threadIdx.x;
  if (o < 256) {
    const float N = 32.f * 3136.f;
    const float m = bnsum[o] / N;
    const float v = bnsq[o] / N - m * m;
    const float sc = bn_g[o] / sqrtf(v + 1e-5f);
    scale[o] = sc;
    shift[o] = bn_b[o] - m * sc;
  }
}

__global__ __launch_bounds__(256) void k_bnapply(float* __restrict__ z,
                                                 const float* __restrict__ scale,
                                                 const float* __restrict__ shift) {
  const size_t i = ((size_t)blockIdx.x * 256 + threadIdx.x) * 4;
  const int ch = (int)((i / 3136) & 255);
  const float sc = scale[ch], sh = shift[ch];
  float4 v = *(float4*)(z + i);
  v.x = fmaf(v.x, sc, sh);
  v.y = fmaf(v.y, sc, sh);
  v.z = fmaf(v.z, sc, sh);
  v.w = fmaf(v.w, sc, sh);
  *(float4*)(z + i) = v;
}

extern "C" void kernel_launch(void* const* d_in, const int* in_sizes, int n_in,
                              void* d_out, int out_size, void* d_ws, size_t ws_size,
                              hipStream_t stream) {
  const float* x          = (const float*)d_in[0];
  const float* fc1_w      = (const float*)d_in[1];
  const float* fc1_b      = (const float*)d_in[2];
  const float* ln_g       = (const float*)d_in[3];
  const float* ln_b       = (const float*)d_in[4];
  const float* fh_w       = (const float*)d_in[5];
  const float* fh_b       = (const float*)d_in[6];
  const float* basis_real = (const float*)d_in[7];
  const float* basis_imag = (const float*)d_in[8];
  const float* conv_w     = (const float*)d_in[9];
  const float* bn_g       = (const float*)d_in[10];
  const float* bn_b       = (const float*)d_in[11];
  float* out = (float*)d_out;
  char* ws = (char*)d_ws;
  (void)in_sizes; (void)n_in; (void)out_size; (void)ws_size;

  float* ctx   = (float*)(ws + WO_CTX);
  float* hdn   = (float*)(ws + WO_HDN);
  float* bnsum = (float*)(ws + WO_BNSUM);
  float* bnsq  = (float*)(ws + WO_BNSQ);
  float* scale = (float*)(ws + WO_SCALE);
  float* shift = (float*)(ws + WO_SHIFT);
  float* coef  = (float*)(ws + WO_COEF);
  ushort_t* BmT_h  = (ushort_t*)(ws + WO_BMT_H);
  ushort_t* BmT_l  = (ushort_t*)(ws + WO_BMT_L);
  ushort_t* FARe_h = (ushort_t*)(ws + WO_FARE_H);
  ushort_t* FARe_l = (ushort_t*)(ws + WO_FARE_L);
  ushort_t* FAIm_h = (ushort_t*)(ws + WO_FAIM_H);
  ushort_t* FAIm_l = (ushort_t*)(ws + WO_FAIM_L);
  ushort_t* FDRe_h = (ushort_t*)(ws + WO_FDRE_H);
  ushort_t* FDRe_l = (ushort_t*)(ws + WO_FDRE_L);
  ushort_t* FDIm_h = (ushort_t*)(ws + WO_FDIM_H);
  ushort_t* FDIm_l = (ushort_t*)(ws + WO_FDIM_L);
  ushort_t* DtT_h  = (ushort_t*)(ws + WO_DTT_H);
  ushort_t* DtT_l  = (ushort_t*)(ws + WO_DTT_L);
  ushort_t* W_h    = (ushort_t*)(ws + WO_CW_H);
  ushort_t* W_l    = (ushort_t*)(ws + WO_CW_L);
  float*    basP   = (float*)(ws + WO_BASP);
  ushort_t* ybf    = (ushort_t*)(ws + WO_YBF);

  hipMemsetAsync(bnsum, 0, 2048, stream);  // bnsum+bnsq contiguous

  hipLaunchKernelGGL(k_const, dim3(528), dim3(256), 0, stream,
                     conv_w, basis_real, basis_imag,
                     BmT_h, BmT_l, FARe_h, FARe_l, FAIm_h, FAIm_l,
                     FDRe_h, FDRe_l, FDIm_h, FDIm_l, DtT_h, DtT_l, W_h, W_l, basP);
  hipLaunchKernelGGL(k_gap, dim3(8192), dim3(256), 0, stream, x, ctx);
  hipLaunchKernelGGL(k_mlp, dim3(32), dim3(64), 0, stream,
                     ctx, fc1_w, fc1_b, ln_g, ln_b, hdn);
  hipLaunchKernelGGL(k_coeffs, dim3(512), dim3(256), 0, stream, hdn, fh_w, fh_b, coef);
  hipLaunchKernelGGL(k_fft, dim3(2048), dim3(256), 0, stream,
                     x, coef, basP,
                     BmT_h, BmT_l, FARe_h, FARe_l, FAIm_h, FAIm_l,
                     FDRe_h, FDRe_l, FDIm_h, FDIm_l, DtT_h, DtT_l, ybf);
  hipLaunchKernelGGL(k_conv, dim3(13, 2, 32), dim3(256), 0, stream,
                     ybf, W_h, W_l, out, bnsum, bnsq);
  hipLaunchKernelGGL(k_bnstats, dim3(1), dim3(256), 0, stream,
                     bnsum, bnsq, bn_g, bn_b, scale, shift);
  hipLaunchKernelGGL(k_bnapply, dim3(25088), dim3(256), 0, stream, out, scale, shift);
}